// Round 6
// baseline (263.715 us; speedup 1.0000x reference)
//
#include <hip/hip_runtime.h>
#include <hip/hip_fp16.h>
#include <hip/hip_cooperative_groups.h>

namespace cg = cooperative_groups;

#define N_SAMP 8192
#define C_CLS  1000
#define A_DIM  2048
#define KDIM   4096   // 2*A_DIM (term1 | term3 folded)
#define CP     1024   // padded C
#define ZSPLIT 8
#define KS     (KDIM / ZSPLIT)   // 512
#define NTILE  (KS / 32)         // 16
#define NBLK   512
#define NTHR   256

typedef _Float16 half8 __attribute__((ext_vector_type(8)));
typedef _Float16 half4 __attribute__((ext_vector_type(4)));
typedef float    f32x4 __attribute__((ext_vector_type(4)));

// One cooperative kernel, 5 phases separated by grid.sync():
//  1. prep:   A' = [cv | -2*fc*cv], B' = [fc^2 | fc]  (f16, zero-padded rows)
//  2. gemm:   Spart[z] = A'[:,zKS:...] * B'[:,...]^T  (m97 structure, f16 out)
//  3. ksum:   S = sum_z Spart[z]                      (f32 accum, f16 out)
//  4. row_nll: per-wave LSE over 4 samples; per-row term2 cancels in LSE diff
//  5. finalize: block 0 reduces 2048 partial pairs -> out
__global__ __launch_bounds__(NTHR, 2) void fused_kernel(
    const float* __restrict__ fc, const float* __restrict__ cv,
    const float* __restrict__ y_s, const int* __restrict__ labels,
    const float* __restrict__ ratio, const float* __restrict__ weights,
    _Float16* __restrict__ Ab, _Float16* __restrict__ Bb,
    _Float16* __restrict__ Spart, _Float16* __restrict__ S,
    float* __restrict__ part, float* __restrict__ out)
{
    cg::grid_group grid = cg::this_grid();
    const int tid = threadIdx.x;
    const int bid = blockIdx.x;
    const int gid = bid * NTHR + tid;

    __shared__ _Float16 As[2][128][32];
    __shared__ _Float16 Bs[2][128][32];

    // ---------------- phase 1: prep ----------------
    #pragma unroll
    for (int it = 0; it < 4; ++it) {
        int i4 = it * (NBLK * NTHR) + gid;   // 4*131072 = CP*A_DIM/4
        int c  = i4 >> 9;                    // A_DIM/4 = 512
        int k4 = i4 & 511;
        f32x4 f = {0.f,0.f,0.f,0.f}, v = {0.f,0.f,0.f,0.f};
        if (c < C_CLS) {
            size_t off = (size_t)c * (A_DIM / 4) + k4;
            f = ((const f32x4*)fc)[off];
            v = ((const f32x4*)cv)[off];
        }
        half4 aL, aR, bL, bR;
        #pragma unroll
        for (int t = 0; t < 4; t++) {
            aL[t] = (_Float16)v[t];
            aR[t] = (_Float16)(-2.f * f[t] * v[t]);
            bL[t] = (_Float16)(f[t] * f[t]);
            bR[t] = (_Float16)f[t];
        }
        size_t ro = (size_t)c * KDIM + k4 * 4;
        *(half4*)(Ab + ro)         = aL;
        *(half4*)(Ab + ro + A_DIM) = aR;
        *(half4*)(Bb + ro)         = bL;
        *(half4*)(Bb + ro + A_DIM) = bR;
    }
    grid.sync();

    // ---------------- phase 2: gemm ----------------
    {
        int z  = bid & 7;            // bid%8 = XCD id (round-robin dispatch):
        int tc = (bid >> 3) & 7;     // each K-slice stays on one XCD (L2-resident)
        int tj = bid >> 6;
        int lane = tid & 63;
        int w    = tid >> 6;
        int wr = w >> 1, wc = w & 1;
        int k0 = z * KS;
        const size_t arow0 = (size_t)tc * 128;
        const size_t brow0 = (size_t)tj * 128;

#define STAGE(p, kcur)                                                                  \
    {                                                                                   \
        _Pragma("unroll")                                                               \
        for (int issue = 0; issue < 2; ++issue) {                                       \
            int t16 = issue * 256 + tid;                                                \
            int row = t16 >> 2, gp = t16 & 3;                                           \
            int gs  = gp ^ ((row >> 1) & 3);                                            \
            const _Float16* ga = Ab + (arow0 + row) * KDIM + (kcur) + gs * 8;           \
            const _Float16* gb = Bb + (brow0 + row) * KDIM + (kcur) + gs * 8;           \
            char* la = (char*)&As[p][0][0] + (issue * 256 + w * 64) * 16;               \
            char* lb = (char*)&Bs[p][0][0] + (issue * 256 + w * 64) * 16;               \
            __builtin_amdgcn_global_load_lds(                                           \
                (const __attribute__((address_space(1))) void*)ga,                      \
                (__attribute__((address_space(3))) void*)la, 16, 0, 0);                 \
            __builtin_amdgcn_global_load_lds(                                           \
                (const __attribute__((address_space(1))) void*)gb,                      \
                (__attribute__((address_space(3))) void*)lb, 16, 0, 0);                 \
        }                                                                               \
    }

        f32x4 acc[4][4] = {};
        int r16 = lane & 15;
        int g   = lane >> 4;

        STAGE(0, k0);
        __syncthreads();
        for (int t = 0; t < NTILE; ++t) {
            int cur = t & 1;
            if (t + 1 < NTILE) STAGE(cur ^ 1, k0 + (t + 1) * 32);
            half8 af[4], bf[4];
            #pragma unroll
            for (int m = 0; m < 4; m++) {
                int row = wr * 64 + m * 16 + r16;
                af[m] = *(const half8*)&As[cur][row][(g ^ ((row >> 1) & 3)) * 8];
            }
            #pragma unroll
            for (int n = 0; n < 4; n++) {
                int row = wc * 64 + n * 16 + r16;
                bf[n] = *(const half8*)&Bs[cur][row][(g ^ ((row >> 1) & 3)) * 8];
            }
            #pragma unroll
            for (int m = 0; m < 4; m++)
                #pragma unroll
                for (int n = 0; n < 4; n++)
                    acc[m][n] = __builtin_amdgcn_mfma_f32_16x16x32_f16(af[m], bf[n], acc[m][n], 0, 0, 0);
            __syncthreads();
        }
#undef STAGE

        // C/D layout (verified m89): col = lane&15, row = (lane>>4)*4 + r
        _Float16* Sp = Spart + (size_t)z * CP * CP;
        int drow = (lane >> 4) * 4;
        int dcol = lane & 15;
        #pragma unroll
        for (int m = 0; m < 4; m++)
            #pragma unroll
            for (int n = 0; n < 4; n++)
                #pragma unroll
                for (int r = 0; r < 4; r++)
                    Sp[(size_t)(tc * 128 + wr * 64 + m * 16 + drow + r) * CP
                       + tj * 128 + wc * 64 + n * 16 + dcol] = (_Float16)acc[m][n][r];
    }
    grid.sync();

    // ---------------- phase 3: ksum ----------------
    {
        size_t idx = (size_t)gid;            // CP*CP/8 = 131072 = exactly 1/thread
        float a[8] = {};
        #pragma unroll
        for (int z = 0; z < ZSPLIT; z++) {
            half8 vv = ((const half8*)(Spart + (size_t)z * CP * CP))[idx];
            #pragma unroll
            for (int t = 0; t < 8; t++) a[t] += (float)vv[t];
        }
        half8 o;
        #pragma unroll
        for (int t = 0; t < 8; t++) o[t] = (_Float16)a[t];
        ((half8*)S)[idx] = o;
    }
    grid.sync();

    // ---------------- phase 4: row_nll ----------------
    {
        int lane = tid & 63;
        int w    = tid >> 6;
        int slot = bid * 4 + w;              // 2048 wave-slots, 4 samples each
        float h = 0.5f * ratio[0];
        float wn = 0.f, ww = 0.f;
        for (int r = 0; r < 4; r++) {
            int i = slot * 4 + r;
            int y = labels[i];
            const float*    ys_row = y_s + (size_t)i * C_CLS;
            const _Float16* s_row  = S   + (size_t)y * CP;

            float v[16];
            float m = -INFINITY, target = -INFINITY;
            #pragma unroll
            for (int k = 0; k < 4; k++) {
                int j = lane * 4 + 256 * k;   // j<1000 => j+3<=999
                if (j < C_CLS) {
                    f32x4 ys = *(const f32x4*)(ys_row + j);
                    half4 sv = *(const half4*)(s_row + j);
                    #pragma unroll
                    for (int t = 0; t < 4; t++) {
                        float val = ys[t] + h * (float)sv[t];
                        v[k * 4 + t] = val;
                        m = fmaxf(m, val);
                        if (j + t == y) target = val;
                    }
                } else {
                    #pragma unroll
                    for (int t = 0; t < 4; t++) v[k * 4 + t] = -INFINITY;
                }
            }
            #pragma unroll
            for (int off = 32; off; off >>= 1) m = fmaxf(m, __shfl_xor(m, off));
            float s = 0.f;
            #pragma unroll
            for (int k = 0; k < 16; k++) s += __expf(v[k] - m);
            #pragma unroll
            for (int off = 32; off; off >>= 1) s += __shfl_xor(s, off);
            #pragma unroll
            for (int off = 32; off; off >>= 1) target = fmaxf(target, __shfl_xor(target, off));
            // m, s, target now wave-uniform
            float wgt = weights[y];
            wn += wgt * ((m + logf(s)) - target);
            ww += wgt;
        }
        if (lane == 0) { part[2 * slot] = wn; part[2 * slot + 1] = ww; }
    }
    grid.sync();

    // ---------------- phase 5: finalize ----------------
    if (bid == 0) {
        float a = 0.f, b = 0.f;
        for (int i = tid; i < 2048; i += NTHR) {
            a += part[2 * i];
            b += part[2 * i + 1];
        }
        #pragma unroll
        for (int off = 32; off; off >>= 1) { a += __shfl_xor(a, off); b += __shfl_xor(b, off); }
        __shared__ float wa[4], wb[4];
        int w = tid >> 6;
        if ((tid & 63) == 0) { wa[w] = a; wb[w] = b; }
        __syncthreads();
        if (tid == 0)
            out[0] = (wa[0] + wa[1] + wa[2] + wa[3]) / (wb[0] + wb[1] + wb[2] + wb[3]);
    }
}

extern "C" void kernel_launch(void* const* d_in, const int* in_sizes, int n_in,
                              void* d_out, int out_size, void* d_ws, size_t ws_size,
                              hipStream_t stream) {
    const float* fc      = (const float*)d_in[0];
    // d_in[1] = features_source (unused by reference)
    const float* y_s     = (const float*)d_in[2];
    const int*   labels  = (const int*)d_in[3];
    const float* ratio   = (const float*)d_in[4];
    const float* weights = (const float*)d_in[5];
    const float* cv      = (const float*)d_in[6];

    char* ws = (char*)d_ws;
    _Float16* Abuf  = (_Float16*)ws;                                  // [0, 8 MB)
    _Float16* Bbuf  = (_Float16*)(ws + (size_t)8 * 1024 * 1024);      // [8, 16 MB)
    _Float16* Spart = (_Float16*)(ws + (size_t)16 * 1024 * 1024);     // 8 * 2 MB
    _Float16* S     = (_Float16*)ws;   // reuses Abuf region (dead after gemm)
    float*    part  = (float*)   (ws + (size_t)32 * 1024 * 1024);     // 16 KB
    float*    outp  = (float*)d_out;

    void* args[] = { (void*)&fc, (void*)&cv, (void*)&y_s, (void*)&labels,
                     (void*)&ratio, (void*)&weights, (void*)&Abuf, (void*)&Bbuf,
                     (void*)&Spart, (void*)&S, (void*)&part, (void*)&outp };
    hipLaunchCooperativeKernel((const void*)fused_kernel, dim3(NBLK), dim3(NTHR),
                               args, 0, stream);
}

// Round 7
// 217.321 us; speedup vs baseline: 1.2135x; 1.2135x over previous
//
#include <hip/hip_runtime.h>
#include <hip/hip_fp16.h>

#define N_SAMP 8192
#define C_CLS  1000
#define A_DIM  2048
#define KDIM   4096   // 2*A_DIM (term1 | term3 folded)
#define CP     1024   // padded C
#define ZSPLIT 8

typedef _Float16 half8 __attribute__((ext_vector_type(8)));
typedef _Float16 half4 __attribute__((ext_vector_type(4)));
typedef float    f32x4 __attribute__((ext_vector_type(4)));

// Spart[z] = A'[:,zKS:(z+1)KS] * B'[:,...]^T with A' = [cv | -2*fc*cv],
// B' = [fc^2 | fc] generated ON THE FLY from f32 fc/cv (prep kernel folded in).
// Reg-staged: LOAD(t+1) issued before compute(t) (T14 split), ds_write after
// the post-compute barrier. Slot geometry + granule XOR-swizzle identical to
// the verified global_load_lds version (slot s: row=s>>2, phys granule s&3
// holds logical granule (s&3)^((row>>1)&3); read addr applies same XOR).
// blockIdx.x = z -> linear%8 = XCD id: each K-slice stays on one XCD (<=4MB L2).
template<int Z>
__global__ __launch_bounds__(256) void gemm_kernel(const float* __restrict__ fc,
                                                   const float* __restrict__ cv,
                                                   _Float16* __restrict__ Spart,
                                                   unsigned* __restrict__ counter) {
    constexpr int KS = KDIM / Z;      // 512
    constexpr int NT = KS / 32;       // 16
    __shared__ _Float16 As[128][32];
    __shared__ _Float16 Bs[128][32];

    const int z  = blockIdx.x;
    const int tj = blockIdx.y;
    const int tc = blockIdx.z;
    const int tid = threadIdx.x;
    if (z == 0 && tj == 0 && tc == 0 && tid == 0) *counter = 0;  // init for row_nll ticket
    const int lane = tid & 63;
    const int w  = tid >> 6;
    const int wr = w >> 1, wc = w & 1;
    const bool hi = (z >= Z / 2);                 // hi half: k >= A_DIM
    const int kbase = (hi ? (z - Z / 2) : z) * KS; // col offset within fc/cv

    // fixed per-thread slot geometry (2 slots: 512 slots of 16B per matrix)
    int row_[2], gs_[2], arow_[2], brow_[2];
    #pragma unroll
    for (int is = 0; is < 2; is++) {
        int t16 = is * 256 + tid;
        int row = t16 >> 2, gp = t16 & 3;
        row_[is]  = row;
        gs_[is]   = gp ^ ((row >> 1) & 3);
        arow_[is] = tc * 128 + row;
        brow_[is] = tj * 128 + row;
    }

    f32x4 cva[2][2] = {}, fca[2][2] = {}, fcb[2][2] = {};

#define LOADT(t)                                                          \
    {                                                                     \
        _Pragma("unroll")                                                 \
        for (int is = 0; is < 2; is++) {                                  \
            int kk = kbase + (t) * 32 + gs_[is] * 8;                      \
            f32x4 zer = {0.f, 0.f, 0.f, 0.f};                             \
            bool va = arow_[is] < C_CLS, vb = brow_[is] < C_CLS;          \
            const float* pa = cv + (size_t)arow_[is] * A_DIM + kk;        \
            const float* pf = fc + (size_t)arow_[is] * A_DIM + kk;        \
            const float* pb = fc + (size_t)brow_[is] * A_DIM + kk;        \
            cva[is][0] = va ? *(const f32x4*)pa : zer;                    \
            cva[is][1] = va ? *(const f32x4*)(pa + 4) : zer;              \
            if (hi) {                                                     \
                fca[is][0] = va ? *(const f32x4*)pf : zer;                \
                fca[is][1] = va ? *(const f32x4*)(pf + 4) : zer;          \
            }                                                             \
            fcb[is][0] = vb ? *(const f32x4*)pb : zer;                    \
            fcb[is][1] = vb ? *(const f32x4*)(pb + 4) : zer;              \
        }                                                                 \
    }

#define WRITET()                                                          \
    {                                                                     \
        _Pragma("unroll")                                                 \
        for (int is = 0; is < 2; is++) {                                  \
            half8 av, bv;                                                 \
            _Pragma("unroll")                                             \
            for (int q = 0; q < 2; q++)                                   \
                _Pragma("unroll")                                         \
                for (int j = 0; j < 4; j++) {                             \
                    float vv = cva[is][q][j];                             \
                    float fa = fca[is][q][j];                             \
                    float fb = fcb[is][q][j];                             \
                    av[q * 4 + j] = (_Float16)(hi ? (-2.f * fa * vv) : vv); \
                    bv[q * 4 + j] = (_Float16)(hi ? fb : (fb * fb));      \
                }                                                         \
            int t16 = is * 256 + tid;                                     \
            *(half8*)((char*)&As[0][0] + t16 * 16) = av;                  \
            *(half8*)((char*)&Bs[0][0] + t16 * 16) = bv;                  \
        }                                                                 \
    }

    f32x4 acc[4][4] = {};
    const int r16 = lane & 15;
    const int g   = lane >> 4;

    LOADT(0);
    WRITET();
    __syncthreads();
    for (int t = 0; t < NT; ++t) {
        if (t + 1 < NT) LOADT(t + 1);        // issue next loads; hide under compute
        half8 af[4], bf[4];
        #pragma unroll
        for (int m = 0; m < 4; m++) {
            int row = wr * 64 + m * 16 + r16;
            af[m] = *(const half8*)&As[row][(g ^ ((row >> 1) & 3)) * 8];
        }
        #pragma unroll
        for (int n = 0; n < 4; n++) {
            int row = wc * 64 + n * 16 + r16;
            bf[n] = *(const half8*)&Bs[row][(g ^ ((row >> 1) & 3)) * 8];
        }
        #pragma unroll
        for (int m = 0; m < 4; m++)
            #pragma unroll
            for (int n = 0; n < 4; n++)
                acc[m][n] = __builtin_amdgcn_mfma_f32_16x16x32_f16(af[m], bf[n], acc[m][n], 0, 0, 0);
        __syncthreads();                      // all waves done reading LDS
        if (t + 1 < NT) {
            WRITET();                         // vm-wait + ds_write next tile
            __syncthreads();                  // writes visible before next reads
        }
    }
#undef LOADT
#undef WRITET

    // C/D layout (verified m89): col = lane&15, row = (lane>>4)*4 + r
    _Float16* Sp = Spart + (size_t)z * CP * CP;
    int drow = (lane >> 4) * 4;
    int dcol = lane & 15;
    #pragma unroll
    for (int m = 0; m < 4; m++)
        #pragma unroll
        for (int n = 0; n < 4; n++)
            #pragma unroll
            for (int r = 0; r < 4; r++)
                Sp[(size_t)(tc * 128 + wr * 64 + m * 16 + drow + r) * CP
                   + tj * 128 + wc * 64 + n * 16 + dcol] = (_Float16)acc[m][n][r];
}

// S = sum_z Spart[z] (f16 in, f32 accumulate, f16 out).  Compact 2 MB S then
// serves row_nll's label-random row reads from L2/L3 (round-3 lesson: fusing
// this into row_nll re-fetched ~100 MB from HBM).
template<int Z>
__global__ __launch_bounds__(256) void ksum_kernel(const _Float16* __restrict__ Spart,
                                                   _Float16* __restrict__ S) {
    size_t idx = (size_t)blockIdx.x * 256 + threadIdx.x;   // over CP*CP/8 half8s
    float a[8] = {};
    #pragma unroll
    for (int z = 0; z < Z; z++) {
        half8 v = ((const half8*)(Spart + (size_t)z * CP * CP))[idx];
        #pragma unroll
        for (int t = 0; t < 8; t++) a[t] += (float)v[t];
    }
    half8 o;
    #pragma unroll
    for (int t = 0; t < 8; t++) o[t] = (_Float16)a[t];
    ((half8*)S)[idx] = o;
}

// One wave per sample-slot: nll_i = LSE_j(y_s[i,j] + h*S[y_i,j]) - value at
// j=y_i (per-row term2 cancels in the LSE difference). Block partials; the
// LAST block (atomic ticket) reduces all partials -> out (finalize folded in,
// fixed reduction order => deterministic).
__global__ __launch_bounds__(256) void row_nll_kernel(const float* __restrict__ y_s,
                                                      const _Float16* __restrict__ S,
                                                      const int* __restrict__ labels,
                                                      const float* __restrict__ ratio,
                                                      const float* __restrict__ weights,
                                                      float* __restrict__ partial,
                                                      unsigned* __restrict__ counter,
                                                      float* __restrict__ out) {
    int lane = threadIdx.x & 63;
    int w = threadIdx.x >> 6;
    int i = blockIdx.x * 4 + w;
    int y = labels[i];
    float h = 0.5f * ratio[0];
    const float*    ys_row = y_s + (size_t)i * C_CLS;
    const _Float16* s_row  = S   + (size_t)y * CP;

    float v[16];
    float m = -INFINITY, target = -INFINITY;
    #pragma unroll
    for (int k = 0; k < 4; k++) {
        int j = lane * 4 + 256 * k;          // multiple of 4; j<1000 => j+3<=999
        if (j < C_CLS) {
            f32x4 ys = *(const f32x4*)(ys_row + j);
            half4 sv = *(const half4*)(s_row + j);
            #pragma unroll
            for (int t = 0; t < 4; t++) {
                float val = ys[t] + h * (float)sv[t];
                v[k * 4 + t] = val;
                m = fmaxf(m, val);
                if (j + t == y) target = val;
            }
        } else {
            #pragma unroll
            for (int t = 0; t < 4; t++) v[k * 4 + t] = -INFINITY;
        }
    }
    #pragma unroll
    for (int off = 32; off; off >>= 1) m = fmaxf(m, __shfl_xor(m, off));
    float s = 0.f;
    #pragma unroll
    for (int k = 0; k < 16; k++) s += __expf(v[k] - m);  // exp(-inf)=0 for padding
    #pragma unroll
    for (int off = 32; off; off >>= 1) s += __shfl_xor(s, off);
    #pragma unroll
    for (int off = 32; off; off >>= 1) target = fmaxf(target, __shfl_xor(target, off));

    __shared__ float swn[4], sww[4];
    if (lane == 0) {
        float wgt = weights[y];
        swn[w] = wgt * ((m + logf(s)) - target);
        sww[w] = wgt;
    }
    __syncthreads();
    if (threadIdx.x == 0) {
        partial[2 * blockIdx.x]     = swn[0] + swn[1] + swn[2] + swn[3];
        partial[2 * blockIdx.x + 1] = sww[0] + sww[1] + sww[2] + sww[3];
    }

    // ---- folded finalize: last block reduces all block partials ----
    __threadfence();                          // make this block's partial visible
    __shared__ bool last;
    if (threadIdx.x == 0) {
        unsigned old = atomicAdd(counter, 1u);
        last = (old == (unsigned)(gridDim.x - 1));
    }
    __syncthreads();
    if (last) {
        __threadfence();                      // acquire: see all partials
        float a = 0.f, b = 0.f;
        for (int t = threadIdx.x; t < (int)gridDim.x; t += 256) {
            a += partial[2 * t];
            b += partial[2 * t + 1];
        }
        #pragma unroll
        for (int off = 32; off; off >>= 1) { a += __shfl_xor(a, off); b += __shfl_xor(b, off); }
        __shared__ float wa[4], wb[4];
        if (lane == 0) { wa[w] = a; wb[w] = b; }
        __syncthreads();
        if (threadIdx.x == 0) {
            out[0] = (wa[0] + wa[1] + wa[2] + wa[3]) / (wb[0] + wb[1] + wb[2] + wb[3]);
            *counter = 0;                     // leave clean (gemm re-zeroes anyway)
        }
    }
}

#define NBLK_NLL (N_SAMP / 4)

extern "C" void kernel_launch(void* const* d_in, const int* in_sizes, int n_in,
                              void* d_out, int out_size, void* d_ws, size_t ws_size,
                              hipStream_t stream) {
    const float* fc      = (const float*)d_in[0];
    // d_in[1] = features_source (unused by reference)
    const float* y_s     = (const float*)d_in[2];
    const int*   labels  = (const int*)d_in[3];
    const float* ratio   = (const float*)d_in[4];
    const float* weights = (const float*)d_in[5];
    const float* cv      = (const float*)d_in[6];

    char* ws = (char*)d_ws;
    _Float16* Spart   = (_Float16*)ws;                                   // 8 * 2 MB
    _Float16* S       = (_Float16*)(ws + (size_t)16 * 1024 * 1024);      // 2 MB
    float*    part    = (float*)   (ws + (size_t)18 * 1024 * 1024);      // 16 KB
    unsigned* counter = (unsigned*)(ws + (size_t)18 * 1024 * 1024 + 32768);

    gemm_kernel<ZSPLIT><<<dim3(ZSPLIT, 8, 8), 256, 0, stream>>>(fc, cv, Spart, counter);
    ksum_kernel<ZSPLIT><<<(CP * CP / 8) / 256, 256, 0, stream>>>(Spart, S);
    row_nll_kernel<<<NBLK_NLL, 256, 0, stream>>>(y_s, S, labels, ratio, weights,
                                                 part, counter, (float*)d_out);
}

// Round 8
// 46.022 us; speedup vs baseline: 5.7301x; 4.7221x over previous
//
#include <hip/hip_runtime.h>
#include <hip/hip_fp16.h>

#define N_SAMP 8192
#define C_CLS  1000
#define A_DIM  2048
#define KDIM   4096   // 2*A_DIM (term1 | term3 folded)
#define CP     1024   // padded C
#define ZSPLIT 8

typedef _Float16 half8 __attribute__((ext_vector_type(8)));
typedef _Float16 half4 __attribute__((ext_vector_type(4)));
typedef float    f32x4 __attribute__((ext_vector_type(4)));

// Spart[z] = A'[:,zKS:(z+1)KS] * B'[:,...]^T with A' = [cv | -2*fc*cv],
// B' = [fc^2 | fc] generated ON THE FLY from f32 fc/cv (prep folded in).
// Reg-staged: LOAD(t+1) issued before compute(t) (T14 split), ds_write after
// the post-compute barrier. Granule XOR-swizzle on both sides (rule #21).
// blockIdx.x = z -> linear%8 = XCD id: each K-slice stays on one XCD (<=4MB L2).
// NO device-scope fences/atomics anywhere (round-6/7 lesson: grid.sync and
// threadfence tickets cost 50-200us on gfx950's non-coherent L2s).
template<int Z>
__global__ __launch_bounds__(256) void gemm_kernel(const float* __restrict__ fc,
                                                   const float* __restrict__ cv,
                                                   _Float16* __restrict__ Spart) {
    constexpr int KS = KDIM / Z;      // 512
    constexpr int NT = KS / 32;       // 16
    __shared__ _Float16 As[128][32];
    __shared__ _Float16 Bs[128][32];

    const int z  = blockIdx.x;
    const int tj = blockIdx.y;
    const int tc = blockIdx.z;
    const int tid = threadIdx.x;
    const int lane = tid & 63;
    const int w  = tid >> 6;
    const int wr = w >> 1, wc = w & 1;
    const bool hi = (z >= Z / 2);                  // hi half: k >= A_DIM
    const int kbase = (hi ? (z - Z / 2) : z) * KS; // col offset within fc/cv

    // fixed per-thread slot geometry (2 slots of 16B per matrix, 512 slots)
    int gs_[2], arow_[2], brow_[2];
    #pragma unroll
    for (int is = 0; is < 2; is++) {
        int t16 = is * 256 + tid;
        int row = t16 >> 2, gp = t16 & 3;
        gs_[is]   = gp ^ ((row >> 1) & 3);
        arow_[is] = tc * 128 + row;
        brow_[is] = tj * 128 + row;
    }

    f32x4 cva[2][2] = {}, fca[2][2] = {}, fcb[2][2] = {};

#define LOADT(t)                                                          \
    {                                                                     \
        _Pragma("unroll")                                                 \
        for (int is = 0; is < 2; is++) {                                  \
            int kk = kbase + (t) * 32 + gs_[is] * 8;                      \
            f32x4 zer = {0.f, 0.f, 0.f, 0.f};                             \
            bool va = arow_[is] < C_CLS, vb = brow_[is] < C_CLS;          \
            const float* pa = cv + (size_t)arow_[is] * A_DIM + kk;        \
            const float* pf = fc + (size_t)arow_[is] * A_DIM + kk;        \
            const float* pb = fc + (size_t)brow_[is] * A_DIM + kk;        \
            cva[is][0] = va ? *(const f32x4*)pa : zer;                    \
            cva[is][1] = va ? *(const f32x4*)(pa + 4) : zer;              \
            if (hi) {                                                     \
                fca[is][0] = va ? *(const f32x4*)pf : zer;                \
                fca[is][1] = va ? *(const f32x4*)(pf + 4) : zer;          \
            }                                                             \
            fcb[is][0] = vb ? *(const f32x4*)pb : zer;                    \
            fcb[is][1] = vb ? *(const f32x4*)(pb + 4) : zer;              \
        }                                                                 \
    }

#define WRITET()                                                          \
    {                                                                     \
        _Pragma("unroll")                                                 \
        for (int is = 0; is < 2; is++) {                                  \
            half8 av, bv;                                                 \
            _Pragma("unroll")                                             \
            for (int q = 0; q < 2; q++)                                   \
                _Pragma("unroll")                                         \
                for (int j = 0; j < 4; j++) {                             \
                    float vv = cva[is][q][j];                             \
                    float fa = fca[is][q][j];                             \
                    float fb = fcb[is][q][j];                             \
                    av[q * 4 + j] = (_Float16)(hi ? (-2.f * fa * vv) : vv); \
                    bv[q * 4 + j] = (_Float16)(hi ? fb : (fb * fb));      \
                }                                                         \
            int t16 = is * 256 + tid;                                     \
            *(half8*)((char*)&As[0][0] + t16 * 16) = av;                  \
            *(half8*)((char*)&Bs[0][0] + t16 * 16) = bv;                  \
        }                                                                 \
    }

    f32x4 acc[4][4] = {};
    const int r16 = lane & 15;
    const int g   = lane >> 4;

    LOADT(0);
    WRITET();
    __syncthreads();
    for (int t = 0; t < NT; ++t) {
        if (t + 1 < NT) LOADT(t + 1);        // issue next loads; hide under compute
        half8 af[4], bf[4];
        #pragma unroll
        for (int m = 0; m < 4; m++) {
            int row = wr * 64 + m * 16 + r16;
            af[m] = *(const half8*)&As[row][(g ^ ((row >> 1) & 3)) * 8];
        }
        #pragma unroll
        for (int n = 0; n < 4; n++) {
            int row = wc * 64 + n * 16 + r16;
            bf[n] = *(const half8*)&Bs[row][(g ^ ((row >> 1) & 3)) * 8];
        }
        #pragma unroll
        for (int m = 0; m < 4; m++)
            #pragma unroll
            for (int n = 0; n < 4; n++)
                acc[m][n] = __builtin_amdgcn_mfma_f32_16x16x32_f16(af[m], bf[n], acc[m][n], 0, 0, 0);
        __syncthreads();                      // all waves done reading LDS
        if (t + 1 < NT) {
            WRITET();                         // vm-wait + ds_write next tile
            __syncthreads();                  // writes visible before next reads
        }
    }
#undef LOADT
#undef WRITET

    // C/D layout (verified m89): col = lane&15, row = (lane>>4)*4 + r
    _Float16* Sp = Spart + (size_t)z * CP * CP;
    int drow = (lane >> 4) * 4;
    int dcol = lane & 15;
    #pragma unroll
    for (int m = 0; m < 4; m++)
        #pragma unroll
        for (int n = 0; n < 4; n++)
            #pragma unroll
            for (int r = 0; r < 4; r++)
                Sp[(size_t)(tc * 128 + wr * 64 + m * 16 + drow + r) * CP
                   + tj * 128 + wc * 64 + n * 16 + dcol] = (_Float16)acc[m][n][r];
}

// S = sum_z Spart[z] (f16 in, f32 accumulate, f16 out).  Compact 2 MB S then
// serves row_nll's label-random row reads from L2/L3 (round-3 lesson: fusing
// this into row_nll re-fetched ~100 MB from HBM).
template<int Z>
__global__ __launch_bounds__(256) void ksum_kernel(const _Float16* __restrict__ Spart,
                                                   _Float16* __restrict__ S) {
    size_t idx = (size_t)blockIdx.x * 256 + threadIdx.x;   // over CP*CP/8 half8s
    float a[8] = {};
    #pragma unroll
    for (int z = 0; z < Z; z++) {
        half8 v = ((const half8*)(Spart + (size_t)z * CP * CP))[idx];
        #pragma unroll
        for (int t = 0; t < 8; t++) a[t] += (float)v[t];
    }
    half8 o;
    #pragma unroll
    for (int t = 0; t < 8; t++) o[t] = (_Float16)a[t];
    ((half8*)S)[idx] = o;
}

// One wave per sample: nll_i = LSE_j(y_s[i,j] + h*S[y_i,j]) - value at j=y_i.
// term2 (per-row constant) cancels in the LSE difference. Block partials only;
// NO fences, NO atomics (round-7 lesson).
__global__ __launch_bounds__(256) void row_nll_kernel(const float* __restrict__ y_s,
                                                      const _Float16* __restrict__ S,
                                                      const int* __restrict__ labels,
                                                      const float* __restrict__ ratio,
                                                      const float* __restrict__ weights,
                                                      float* __restrict__ partial) {
    int lane = threadIdx.x & 63;
    int w = threadIdx.x >> 6;
    int i = blockIdx.x * 4 + w;
    int y = labels[i];
    float h = 0.5f * ratio[0];
    const float*    ys_row = y_s + (size_t)i * C_CLS;
    const _Float16* s_row  = S   + (size_t)y * CP;

    float v[16];
    float m = -INFINITY, target = -INFINITY;
    #pragma unroll
    for (int k = 0; k < 4; k++) {
        int j = lane * 4 + 256 * k;          // multiple of 4; j<1000 => j+3<=999
        if (j < C_CLS) {
            f32x4 ys = *(const f32x4*)(ys_row + j);
            half4 sv = *(const half4*)(s_row + j);
            #pragma unroll
            for (int t = 0; t < 4; t++) {
                float val = ys[t] + h * (float)sv[t];
                v[k * 4 + t] = val;
                m = fmaxf(m, val);
                if (j + t == y) target = val;
            }
        } else {
            #pragma unroll
            for (int t = 0; t < 4; t++) v[k * 4 + t] = -INFINITY;
        }
    }
    #pragma unroll
    for (int off = 32; off; off >>= 1) m = fmaxf(m, __shfl_xor(m, off));
    float s = 0.f;
    #pragma unroll
    for (int k = 0; k < 16; k++) s += __expf(v[k] - m);  // exp(-inf)=0 for padding
    #pragma unroll
    for (int off = 32; off; off >>= 1) s += __shfl_xor(s, off);
    #pragma unroll
    for (int off = 32; off; off >>= 1) target = fmaxf(target, __shfl_xor(target, off));

    __shared__ float swn[4], sww[4];
    if (lane == 0) {
        float wgt = weights[y];
        swn[w] = wgt * ((m + logf(s)) - target);
        sww[w] = wgt;
    }
    __syncthreads();
    if (threadIdx.x == 0) {
        partial[2 * blockIdx.x]     = swn[0] + swn[1] + swn[2] + swn[3];
        partial[2 * blockIdx.x + 1] = sww[0] + sww[1] + sww[2] + sww[3];
    }
}

#define NBLK_NLL (N_SAMP / 4)

__global__ __launch_bounds__(256) void finalize_kernel(const float* __restrict__ partial,
                                                       float* __restrict__ out) {
    float a = 0.f, b = 0.f;
    for (int i = threadIdx.x; i < NBLK_NLL; i += 256) {
        a += partial[2 * i];
        b += partial[2 * i + 1];
    }
    #pragma unroll
    for (int off = 32; off; off >>= 1) { a += __shfl_xor(a, off); b += __shfl_xor(b, off); }
    __shared__ float wa[4], wb[4];
    int w = threadIdx.x >> 6;
    if ((threadIdx.x & 63) == 0) { wa[w] = a; wb[w] = b; }
    __syncthreads();
    if (threadIdx.x == 0)
        out[0] = (wa[0] + wa[1] + wa[2] + wa[3]) / (wb[0] + wb[1] + wb[2] + wb[3]);
}

extern "C" void kernel_launch(void* const* d_in, const int* in_sizes, int n_in,
                              void* d_out, int out_size, void* d_ws, size_t ws_size,
                              hipStream_t stream) {
    const float* fc      = (const float*)d_in[0];
    // d_in[1] = features_source (unused by reference)
    const float* y_s     = (const float*)d_in[2];
    const int*   labels  = (const int*)d_in[3];
    const float* ratio   = (const float*)d_in[4];
    const float* weights = (const float*)d_in[5];
    const float* cv      = (const float*)d_in[6];

    char* ws = (char*)d_ws;
    _Float16* Spart = (_Float16*)ws;                                   // 8 * 2 MB
    _Float16* S     = (_Float16*)(ws + (size_t)16 * 1024 * 1024);      // 2 MB
    float*    part  = (float*)   (ws + (size_t)18 * 1024 * 1024);      // 16 KB

    gemm_kernel<ZSPLIT><<<dim3(ZSPLIT, 8, 8), 256, 0, stream>>>(fc, cv, Spart);
    ksum_kernel<ZSPLIT><<<(CP * CP / 8) / 256, 256, 0, stream>>>(Spart, S);
    row_nll_kernel<<<NBLK_NLL, 256, 0, stream>>>(y_s, S, labels, ratio, weights, part);
    finalize_kernel<<<1, 256, 0, stream>>>(part, (float*)d_out);
}

// Round 9
// 39.592 us; speedup vs baseline: 6.6608x; 1.1624x over previous
//
#include <hip/hip_runtime.h>
#include <hip/hip_fp16.h>

#define N_SAMP 8192
#define C_CLS  1000
#define A_DIM  2048
#define KDIM   4096   // 2*A_DIM (term1 | term3 folded), in fp8 bytes
#define CP     1024   // padded C
#define ZSPLIT 8

typedef _Float16 half8 __attribute__((ext_vector_type(8)));
typedef _Float16 half4 __attribute__((ext_vector_type(4)));
typedef float    f32x4 __attribute__((ext_vector_type(4)));

// Scaled fp8 e4m3 operands (values kept in e4m3 normal range; factor 256
// folded out of h in row_nll):
//   A' = [cv | -32*fc*cv],  B' = [256*fc^2 | 16*fc]
//   lo product: cv * 256fc^2 = 256*(cv*fc^2); hi: (-32 fc cv)*(16 fc) = 256*(-2 fc^2 cv)
__global__ __launch_bounds__(256) void prep_kernel(const float* __restrict__ fc,
                                                   const float* __restrict__ cv,
                                                   unsigned char* __restrict__ Ab,
                                                   unsigned char* __restrict__ Bb) {
    int i4 = blockIdx.x * 256 + threadIdx.x;   // over CP*A_DIM/4
    int c  = i4 >> 9;                          // A_DIM/4 = 512
    int k4 = i4 & 511;
    f32x4 f = {0.f, 0.f, 0.f, 0.f}, v = {0.f, 0.f, 0.f, 0.f};
    if (c < C_CLS) {
        size_t off = (size_t)c * (A_DIM / 4) + k4;
        f = ((const f32x4*)fc)[off];
        v = ((const f32x4*)cv)[off];
    }
    int alo = 0, ahi = 0, blo = 0, bhi = 0;
    alo = __builtin_amdgcn_cvt_pk_fp8_f32(v[0], v[1], alo, 0);
    alo = __builtin_amdgcn_cvt_pk_fp8_f32(v[2], v[3], alo, 1);
    ahi = __builtin_amdgcn_cvt_pk_fp8_f32(-32.f * f[0] * v[0], -32.f * f[1] * v[1], ahi, 0);
    ahi = __builtin_amdgcn_cvt_pk_fp8_f32(-32.f * f[2] * v[2], -32.f * f[3] * v[3], ahi, 1);
    blo = __builtin_amdgcn_cvt_pk_fp8_f32(256.f * f[0] * f[0], 256.f * f[1] * f[1], blo, 0);
    blo = __builtin_amdgcn_cvt_pk_fp8_f32(256.f * f[2] * f[2], 256.f * f[3] * f[3], blo, 1);
    bhi = __builtin_amdgcn_cvt_pk_fp8_f32(16.f * f[0], 16.f * f[1], bhi, 0);
    bhi = __builtin_amdgcn_cvt_pk_fp8_f32(16.f * f[2], 16.f * f[3], bhi, 1);
    size_t ro = (size_t)c * KDIM + k4 * 4;     // byte offsets
    *(int*)(Ab + ro)         = alo;
    *(int*)(Ab + ro + A_DIM) = ahi;
    *(int*)(Bb + ro)         = blo;
    *(int*)(Bb + ro + A_DIM) = bhi;
}

// Spart[z] = A'[:,zKS:(z+1)KS] * B'[:,...]^T, fp8 e4m3 operands, f16 out.
// m97 structure at BK=64 fp8 (64B rows = identical granule geometry to the
// verified f16 BK=32 version): 128x128 tile, global_load_lds(16B) staging,
// double-buffered LDS, 4 waves x 64x64, granule XOR-swizzle g^((row>>1)&3)
// applied on the GLOBAL source address + on the ds_read address (rule #21).
// blockIdx.x = z -> linear%8 = XCD id: each K-slice (1MB fp8) L2-resident.
template<int Z>
__global__ __launch_bounds__(256) void gemm_kernel(const unsigned char* __restrict__ A,
                                                   const unsigned char* __restrict__ B,
                                                   _Float16* __restrict__ Spart) {
    constexpr int KS = KDIM / Z;      // 512 bytes/elems of k per slice
    constexpr int NT = KS / 64;       // 8 tile-steps
    __shared__ unsigned char As[2][128][64];
    __shared__ unsigned char Bs[2][128][64];

    const int z  = blockIdx.x;
    const int tj = blockIdx.y;
    const int tc = blockIdx.z;
    const int tid = threadIdx.x;
    const int lane = tid & 63;
    const int w  = tid >> 6;
    const int wr = w >> 1, wc = w & 1;
    const int k0 = z * KS;

    const size_t arow0 = (size_t)tc * 128;
    const size_t brow0 = (size_t)tj * 128;

#define STAGE(p, kcur)                                                                  \
    {                                                                                   \
        _Pragma("unroll")                                                               \
        for (int issue = 0; issue < 2; ++issue) {                                       \
            int t16 = issue * 256 + tid;                                                \
            int row = t16 >> 2, gp = t16 & 3;                                           \
            int gs  = gp ^ ((row >> 1) & 3);                                            \
            const unsigned char* ga = A + (arow0 + row) * KDIM + (kcur) + gs * 16;      \
            const unsigned char* gb = B + (brow0 + row) * KDIM + (kcur) + gs * 16;      \
            char* la = (char*)&As[p][0][0] + t16 * 16;                                  \
            char* lb = (char*)&Bs[p][0][0] + t16 * 16;                                  \
            __builtin_amdgcn_global_load_lds(                                           \
                (const __attribute__((address_space(1))) void*)ga,                      \
                (__attribute__((address_space(3))) void*)la, 16, 0, 0);                 \
            __builtin_amdgcn_global_load_lds(                                           \
                (const __attribute__((address_space(1))) void*)gb,                      \
                (__attribute__((address_space(3))) void*)lb, 16, 0, 0);                 \
        }                                                                               \
    }

    f32x4 acc[4][4] = {};
    const int r16 = lane & 15;
    const int g   = lane >> 4;        // k-group: lane reads 8 fp8 at k = kh*32 + g*8

    STAGE(0, k0);
    __syncthreads();
    for (int t = 0; t < NT; ++t) {
        int cur = t & 1;
        if (t + 1 < NT) STAGE(cur ^ 1, k0 + (t + 1) * 64);
        #pragma unroll
        for (int kh = 0; kh < 2; kh++) {
            // logical 16B granule within the 64B row, then XOR-swizzle
            const int gidx = kh * 2 + (g >> 1);
            const int sub  = (g & 1) * 8;
            long af[4], bf[4];
            #pragma unroll
            for (int m = 0; m < 4; m++) {
                int row = wr * 64 + m * 16 + r16;
                af[m] = *(const long*)&As[cur][row][((gidx ^ ((row >> 1) & 3)) << 4) + sub];
            }
            #pragma unroll
            for (int n = 0; n < 4; n++) {
                int row = wc * 64 + n * 16 + r16;
                bf[n] = *(const long*)&Bs[cur][row][((gidx ^ ((row >> 1) & 3)) << 4) + sub];
            }
            #pragma unroll
            for (int m = 0; m < 4; m++)
                #pragma unroll
                for (int n = 0; n < 4; n++)
                    acc[m][n] = __builtin_amdgcn_mfma_f32_16x16x32_fp8_fp8(af[m], bf[n], acc[m][n], 0, 0, 0);
        }
        __syncthreads();   // drains glds (compiler waitcnt) + guards buffer reuse
    }
#undef STAGE

    // C/D layout (verified m89, dtype-independent): col = lane&15, row = (lane>>4)*4 + r
    _Float16* Sp = Spart + (size_t)z * CP * CP;
    int drow = (lane >> 4) * 4;
    int dcol = lane & 15;
    #pragma unroll
    for (int m = 0; m < 4; m++)
        #pragma unroll
        for (int n = 0; n < 4; n++)
            #pragma unroll
            for (int r = 0; r < 4; r++)
                Sp[(size_t)(tc * 128 + wr * 64 + m * 16 + drow + r) * CP
                   + tj * 128 + wc * 64 + n * 16 + dcol] = (_Float16)acc[m][n][r];
}

// S = sum_z Spart[z] (f16 in, f32 accumulate, f16 out).  Compact 2 MB S then
// serves row_nll's label-random row reads from L2/L3 (round-3 lesson: fusing
// this into row_nll re-fetched ~100 MB from HBM).
template<int Z>
__global__ __launch_bounds__(256) void ksum_kernel(const _Float16* __restrict__ Spart,
                                                   _Float16* __restrict__ S) {
    size_t idx = (size_t)blockIdx.x * 256 + threadIdx.x;   // over CP*CP/8 half8s
    float a[8] = {};
    #pragma unroll
    for (int z = 0; z < Z; z++) {
        half8 v = ((const half8*)(Spart + (size_t)z * CP * CP))[idx];
        #pragma unroll
        for (int t = 0; t < 8; t++) a[t] += (float)v[t];
    }
    half8 o;
    #pragma unroll
    for (int t = 0; t < 8; t++) o[t] = (_Float16)a[t];
    ((half8*)S)[idx] = o;
}

// One wave per sample: nll_i = LSE_j(y_s[i,j] + h*S[y_i,j]) - value at j=y_i.
// term2 (per-row constant) cancels in the LSE difference. h absorbs the 1/256
// fp8 scaling. Block partials only; NO fences, NO atomics (round-7 lesson).
__global__ __launch_bounds__(256) void row_nll_kernel(const float* __restrict__ y_s,
                                                      const _Float16* __restrict__ S,
                                                      const int* __restrict__ labels,
                                                      const float* __restrict__ ratio,
                                                      const float* __restrict__ weights,
                                                      float* __restrict__ partial) {
    int lane = threadIdx.x & 63;
    int w = threadIdx.x >> 6;
    int i = blockIdx.x * 4 + w;
    int y = labels[i];
    float h = 0.5f * ratio[0] * (1.0f / 256.0f);
    const float*    ys_row = y_s + (size_t)i * C_CLS;
    const _Float16* s_row  = S   + (size_t)y * CP;

    float v[16];
    float m = -INFINITY, target = -INFINITY;
    #pragma unroll
    for (int k = 0; k < 4; k++) {
        int j = lane * 4 + 256 * k;          // multiple of 4; j<1000 => j+3<=999
        if (j < C_CLS) {
            f32x4 ys = *(const f32x4*)(ys_row + j);
            half4 sv = *(const half4*)(s_row + j);
            #pragma unroll
            for (int t = 0; t < 4; t++) {
                float val = ys[t] + h * (float)sv[t];
                v[k * 4 + t] = val;
                m = fmaxf(m, val);
                if (j + t == y) target = val;
            }
        } else {
            #pragma unroll
            for (int t = 0; t < 4; t++) v[k * 4 + t] = -INFINITY;
        }
    }
    #pragma unroll
    for (int off = 32; off; off >>= 1) m = fmaxf(m, __shfl_xor(m, off));
    float s = 0.f;
    #pragma unroll
    for (int k = 0; k < 16; k++) s += __expf(v[k] - m);  // exp(-inf)=0 for padding
    #pragma unroll
    for (int off = 32; off; off >>= 1) s += __shfl_xor(s, off);
    #pragma unroll
    for (int off = 32; off; off >>= 1) target = fmaxf(target, __shfl_xor(target, off));

    __shared__ float swn[4], sww[4];
    if (lane == 0) {
        float wgt = weights[y];
        swn[w] = wgt * ((m + logf(s)) - target);
        sww[w] = wgt;
    }
    __syncthreads();
    if (threadIdx.x == 0) {
        partial[2 * blockIdx.x]     = swn[0] + swn[1] + swn[2] + swn[3];
        partial[2 * blockIdx.x + 1] = sww[0] + sww[1] + sww[2] + sww[3];
    }
}

#define NBLK_NLL (N_SAMP / 4)

__global__ __launch_bounds__(256) void finalize_kernel(const float* __restrict__ partial,
                                                       float* __restrict__ out) {
    float a = 0.f, b = 0.f;
    for (int i = threadIdx.x; i < NBLK_NLL; i += 256) {
        a += partial[2 * i];
        b += partial[2 * i + 1];
    }
    #pragma unroll
    for (int off = 32; off; off >>= 1) { a += __shfl_xor(a, off); b += __shfl_xor(b, off); }
    __shared__ float wa[4], wb[4];
    int w = threadIdx.x >> 6;
    if ((threadIdx.x & 63) == 0) { wa[w] = a; wb[w] = b; }
    __syncthreads();
    if (threadIdx.x == 0)
        out[0] = (wa[0] + wa[1] + wa[2] + wa[3]) / (wb[0] + wb[1] + wb[2] + wb[3]);
}

extern "C" void kernel_launch(void* const* d_in, const int* in_sizes, int n_in,
                              void* d_out, int out_size, void* d_ws, size_t ws_size,
                              hipStream_t stream) {
    const float* fc      = (const float*)d_in[0];
    // d_in[1] = features_source (unused by reference)
    const float* y_s     = (const float*)d_in[2];
    const int*   labels  = (const int*)d_in[3];
    const float* ratio   = (const float*)d_in[4];
    const float* weights = (const float*)d_in[5];
    const float* cv      = (const float*)d_in[6];

    char* ws = (char*)d_ws;
    unsigned char* Abuf  = (unsigned char*)ws;                              // [0, 4 MB)
    unsigned char* Bbuf  = (unsigned char*)(ws + (size_t)4 * 1024 * 1024);  // [4, 8 MB)
    _Float16*      Spart = (_Float16*)(ws + (size_t)8 * 1024 * 1024);       // 8 * 2 MB
    _Float16*      S     = (_Float16*)(ws + (size_t)24 * 1024 * 1024);      // 2 MB
    float*         part  = (float*)   (ws + (size_t)26 * 1024 * 1024);      // 16 KB

    prep_kernel<<<(CP * A_DIM / 4) / 256, 256, 0, stream>>>(fc, cv, Abuf, Bbuf);
    gemm_kernel<ZSPLIT><<<dim3(ZSPLIT, 8, 8), 256, 0, stream>>>(Abuf, Bbuf, Spart);
    ksum_kernel<ZSPLIT><<<(CP * CP / 8) / 256, 256, 0, stream>>>(Spart, S);
    row_nll_kernel<<<NBLK_NLL, 256, 0, stream>>>(y_s, S, labels, ratio, weights, part);
    finalize_kernel<<<1, 256, 0, stream>>>(part, (float*)d_out);
}